// Round 1
// baseline (975.883 us; speedup 1.0000x reference)
//
#include <hip/hip_runtime.h>
#include <stdint.h>

// ---------------- problem constants ----------------
#define T_TOK   8192          // B*S
#define D_DIM   1024
#define FF_DIM  4096
#define E_NUM   8
#define SLOT_MAX 17408        // 16384 + 8*128 (worst-case padded slots)
#define RT_MAX  200           // 136 moe row-tiles + 64 dense row-tiles

typedef unsigned int   u32;
typedef unsigned short u16;
typedef __attribute__((ext_vector_type(4))) float  f32x4;
typedef __attribute__((ext_vector_type(4))) float  f4;
typedef __attribute__((ext_vector_type(8))) short  bf16x8;   // 8 bf16 = 4 VGPR (guide §3)
typedef __attribute__((ext_vector_type(8))) unsigned short u16x8;

__device__ __forceinline__ u16 f2bf(float f) {              // RNE f32->bf16
  u32 u = __builtin_bit_cast(u32, f);
  return (u16)((u + 0x7fffu + ((u >> 16) & 1u)) >> 16);
}
__device__ __forceinline__ float bf2f(u16 h) {
  u32 u = ((u32)h) << 16; return __builtin_bit_cast(float, u);
}

typedef const __attribute__((address_space(1))) u32* gp1_t;
typedef __attribute__((address_space(3))) u32*       lp3_t;
__device__ __forceinline__ void gload16(const u16* g, u16* l) {
  // async global->LDS, 16B/lane, dest = wave-uniform base + lane*16
  __builtin_amdgcn_global_load_lds((gp1_t)(const void*)g, (lp3_t)l, 16, 0, 0);
}

// ---------------- K0: zero header ----------------
__global__ void k_init(int* hdr) { if (threadIdx.x < 64) hdr[threadIdx.x] = 0; }

// ---------------- K1: router + gate (wave per token) ----------------
__global__ __launch_bounds__(256) void k_route(
    const float* __restrict__ x, const float* __restrict__ Wr, const float* __restrict__ br,
    const float* __restrict__ Wg, const float* __restrict__ bg,
    int* __restrict__ hdr, int4* __restrict__ tok_sel, float4* __restrict__ tok_wf)
{
  int w = threadIdx.x >> 6, l = threadIdx.x & 63;
  int t = blockIdx.x * 4 + w;
  const float* xt = x + (size_t)t * D_DIM;
  float p[10];
  #pragma unroll
  for (int i = 0; i < 10; ++i) p[i] = 0.f;
  for (int j = 0; j < D_DIM / 64; ++j) {
    int d = j * 64 + l;
    float xv = xt[d];
    p[0] += xv * Wr[d * 2 + 0];
    p[1] += xv * Wr[d * 2 + 1];
    f4 g0 = *(const f4*)&Wg[d * 8];
    f4 g1 = *(const f4*)&Wg[d * 8 + 4];
    p[2] += xv * g0[0]; p[3] += xv * g0[1]; p[4] += xv * g0[2]; p[5] += xv * g0[3];
    p[6] += xv * g1[0]; p[7] += xv * g1[1]; p[8] += xv * g1[2]; p[9] += xv * g1[3];
  }
  #pragma unroll
  for (int off = 32; off; off >>= 1) {
    #pragma unroll
    for (int i = 0; i < 10; ++i) p[i] += __shfl_xor(p[i], off, 64);
  }
  if (l == 0) {
    float a0 = p[0] + br[0], a1 = p[1] + br[1];
    float m  = fmaxf(a0, a1);
    float e0 = __expf(a0 - m), e1 = __expf(a1 - m);
    float rs = 1.f / (e0 + e1);
    float rp0 = e0 * rs, rp1 = e1 * rs;
    float g[E_NUM]; float gm = -1e30f;
    #pragma unroll
    for (int e = 0; e < E_NUM; ++e) { g[e] = p[2 + e] + bg[e]; gm = fmaxf(gm, g[e]); }
    int i0 = 0;
    #pragma unroll
    for (int e = 1; e < E_NUM; ++e) if (g[e] > g[i0]) i0 = e;      // earliest max = top_k tiebreak
    int i1 = (i0 == 0) ? 1 : 0;
    #pragma unroll
    for (int e = 0; e < E_NUM; ++e) if (e != i0 && g[e] > g[i1]) i1 = e;
    float x0 = __expf(g[i0] - gm), x1 = __expf(g[i1] - gm);
    float s = 1.f / (x0 + x1);                                      // == vals/sum(vals) analytically
    int r0 = atomicAdd(&hdr[i0], 1);
    int r1 = atomicAdd(&hdr[i1], 1);
    tok_sel[t] = make_int4(i0, r0, i1, r1);
    tok_wf[t]  = make_float4(x0 * s, x1 * s, rp0, rp1);
  }
}

// ---------------- K2: padded offsets + tile map + perm=-1 ----------------
__global__ __launch_bounds__(256) void k_offsets(int* __restrict__ hdr,
                                                 int4* __restrict__ tilemap,
                                                 int* __restrict__ perm)
{
  __shared__ int soff[E_NUM + 1];
  int tid = threadIdx.x;
  if (tid == 0) {
    int acc = 0;
    for (int e = 0; e < E_NUM; ++e) {
      soff[e] = acc; hdr[8 + e] = acc;
      acc += (hdr[e] + 127) & ~127;                // pad each expert to 128
    }
    soff[E_NUM] = acc;
    hdr[16] = acc;                                 // nslots_padded
    hdr[17] = acc >> 7;                            // moe row-tiles
    hdr[18] = (acc >> 7) + T_TOK / 128;            // total row-tiles
  }
  __syncthreads();
  int nmoe = soff[E_NUM] >> 7;
  for (int rt = tid; rt < RT_MAX; rt += 256) {
    int4 ent;
    if (rt < nmoe) {
      int row0 = rt * 128;
      int e = 0;
      while (e < E_NUM - 1 && row0 >= soff[e + 1]) ++e;
      ent = make_int4(0, row0, e, 0);
    } else if (rt < nmoe + T_TOK / 128) {
      ent = make_int4(1, (rt - nmoe) * 128, -1, 0);
    } else {
      ent = make_int4(-1, 0, 0, 0);
    }
    tilemap[rt] = ent;
  }
  for (int s = tid; s < SLOT_MAX; s += 256) perm[s] = -1;
}

// ---------------- K3: scatter token -> slots ----------------
__global__ void k_scatter(const int4* __restrict__ tok_sel, const int* __restrict__ hdr,
                          int* __restrict__ perm, int2* __restrict__ tok_slot)
{
  int t = blockIdx.x * 256 + threadIdx.x;
  if (t >= T_TOK) return;
  int4 s = tok_sel[t];
  int s0 = hdr[8 + s.x] + s.y;
  int s1 = hdr[8 + s.z] + s.w;
  perm[s0] = t; perm[s1] = t;
  tok_slot[t] = make_int2(s0, s1);
}

// ---------------- K4: cast x -> bf16 ----------------
__global__ void k_cast(const float* __restrict__ x, u16* __restrict__ xb, int n8) {
  int i = blockIdx.x * 256 + threadIdx.x;
  if (i >= n8) return;
  const f4* src = (const f4*)x + (size_t)i * 2;
  f4 a = src[0], b = src[1];
  u16x8 o;
  o[0]=f2bf(a[0]); o[1]=f2bf(a[1]); o[2]=f2bf(a[2]); o[3]=f2bf(a[3]);
  o[4]=f2bf(b[0]); o[5]=f2bf(b[1]); o[6]=f2bf(b[2]); o[7]=f2bf(b[3]);
  ((u16x8*)xb)[i] = o;
}

// ---------------- K5: gather x rows into slot order ----------------
__global__ __launch_bounds__(256) void k_gather(const u16* __restrict__ xb,
                                                const int* __restrict__ perm,
                                                const int* __restrict__ hdr,
                                                u16* __restrict__ xg)
{
  int nslots = hdr[16];
  int row = blockIdx.x * 2 + (threadIdx.x >> 7);
  if (row >= nslots) return;
  int lane = threadIdx.x & 127;
  int t = perm[row];
  u16x8* dst = (u16x8*)(xg + (size_t)row * D_DIM) + lane;
  if (t < 0) { u16x8 z = {0,0,0,0,0,0,0,0}; *dst = z; }
  else       { *dst = *((const u16x8*)(xb + (size_t)t * D_DIM) + lane); }
}

// ---------------- K6: cast+transpose f32 [R,C] -> bf16 [C,R] ----------------
__global__ __launch_bounds__(256) void k_tcast(const float* __restrict__ src,
                                               u16* __restrict__ dst, int R, int C)
{
  const float* s = src + (size_t)blockIdx.z * R * C;
  u16* d = dst + (size_t)blockIdx.z * R * C;
  __shared__ float tile[64][65];
  int tr = blockIdx.y, tc = blockIdx.x;
  int t = threadIdx.x;
  #pragma unroll
  for (int p = 0; p < 4; ++p) {
    int r = p * 16 + (t >> 4);
    int c4 = (t & 15) * 4;
    f4 v = *(const f4*)&s[(size_t)(tr * 64 + r) * C + tc * 64 + c4];
    tile[r][c4+0] = v[0]; tile[r][c4+1] = v[1]; tile[r][c4+2] = v[2]; tile[r][c4+3] = v[3];
  }
  __syncthreads();
  #pragma unroll
  for (int q = 0; q < 2; ++q) {
    int oc = q * 32 + (t >> 3);
    int r8 = (t & 7) * 8;
    u16x8 o;
    #pragma unroll
    for (int j = 0; j < 8; ++j) o[j] = f2bf(tile[r8 + j][oc]);
    *(u16x8*)&d[(size_t)(tc * 64 + oc) * R + tr * 64 + r8] = o;
  }
}

// ---------------- K7/K8: grouped GEMM, m97 structure ----------------
// C[128,128] per block; A [rows,K] bf16 row-major; Bt [cols,K] bf16 row-major.
// 4 waves, each 64x64 via 4x4 x mfma_f32_16x16x32_bf16. BK=32, dbuf LDS,
// global_load_lds width16 (linear LDS, no swizzle -- required).
template <int RELU>
__global__ __launch_bounds__(256) void k_gemm(
    const u16* __restrict__ Amoe, const u16* __restrict__ Aden,
    const u16* __restrict__ Bexp, const u16* __restrict__ Bden,
    const float* __restrict__ biasexp, const float* __restrict__ biasden,
    u16* __restrict__ Omoe, u16* __restrict__ Oden,
    const int* __restrict__ hdr, const int4* __restrict__ tilemap,
    int K, int N, long bexp_stride, int biasexp_stride)
{
  int rt = blockIdx.y;
  if (rt >= hdr[18]) return;
  int4 ent = tilemap[rt];
  const u16* A; const u16* B; const float* bias; u16* O;
  if (ent.x == 1) { A = Aden; B = Bden; bias = biasden; O = Oden; }
  else {
    A = Amoe; B = Bexp + (size_t)ent.z * bexp_stride;
    bias = biasexp + (size_t)ent.z * biasexp_stride; O = Omoe;
  }
  const int row0 = ent.y;
  const int ct = blockIdx.x;

  __shared__ __align__(16) u16 sA[2][128 * 32];
  __shared__ __align__(16) u16 sB[2][128 * 32];

  const int tid = threadIdx.x;
  const int w = tid >> 6, l = tid & 63;

  // staging: wave w, issue i covers LDS bytes [w*2048+i*1024, +1024)
  const u16* aSrc[2]; const u16* bSrc[2];
  u16* ldsA[2][2]; u16* ldsB[2][2];
  #pragma unroll
  for (int i = 0; i < 2; ++i) {
    int r  = w * 32 + i * 16 + (l >> 2);
    int kc = (l & 3) * 8;
    aSrc[i] = A + (size_t)(row0 + r) * K + kc;
    bSrc[i] = B + (size_t)(ct * 128 + r) * K + kc;
    #pragma unroll
    for (int b = 0; b < 2; ++b) {
      ldsA[b][i] = &sA[b][w * 1024 + i * 512];
      ldsB[b][i] = &sB[b][w * 1024 + i * 512];
    }
  }

  f32x4 acc[4][4];
  #pragma unroll
  for (int m = 0; m < 4; ++m)
    #pragma unroll
    for (int n = 0; n < 4; ++n) acc[m][n] = (f32x4){0.f, 0.f, 0.f, 0.f};

  const int NK = K >> 5;

  // prologue
  #pragma unroll
  for (int i = 0; i < 2; ++i) { gload16(aSrc[i], ldsA[0][i]); gload16(bSrc[i], ldsB[0][i]); }
  asm volatile("s_waitcnt vmcnt(0)" ::: "memory");
  __syncthreads();

  const int wrow = (w >> 1) * 64;
  const int wcol = (w & 1) * 64;
  const int fr = l & 15;
  const int fk = (l >> 4) * 8;

  int buf = 0;
  for (int kk = 0; kk < NK; ++kk) {
    if (kk + 1 < NK) {
      int ko = (kk + 1) * 32;
      #pragma unroll
      for (int i = 0; i < 2; ++i) {
        gload16(aSrc[i] + ko, ldsA[buf ^ 1][i]);
        gload16(bSrc[i] + ko, ldsB[buf ^ 1][i]);
      }
    }
    bf16x8 af[4], bfv[4];
    #pragma unroll
    for (int m = 0; m < 4; ++m)
      af[m] = *(const bf16x8*)&sA[buf][(wrow + m * 16 + fr) * 32 + fk];
    #pragma unroll
    for (int n = 0; n < 4; ++n)
      bfv[n] = *(const bf16x8*)&sB[buf][(wcol + n * 16 + fr) * 32 + fk];
    #pragma unroll
    for (int m = 0; m < 4; ++m)
      #pragma unroll
      for (int n = 0; n < 4; ++n)
        acc[m][n] = __builtin_amdgcn_mfma_f32_16x16x32_bf16(af[m], bfv[n], acc[m][n], 0, 0, 0);
    asm volatile("s_waitcnt vmcnt(0)" ::: "memory");
    __syncthreads();
    buf ^= 1;
  }

  // epilogue: C/D layout col=lane&15, row=(lane>>4)*4+reg (measured m89/m91)
  #pragma unroll
  for (int n = 0; n < 4; ++n) {
    int c = ct * 128 + wcol + n * 16 + fr;
    float bv = bias[c];
    #pragma unroll
    for (int m = 0; m < 4; ++m) {
      int rbase = row0 + wrow + m * 16 + (l >> 4) * 4;
      f32x4 v = acc[m][n];
      #pragma unroll
      for (int j = 0; j < 4; ++j) {
        float f = v[j] + bv;
        if (RELU) f = fmaxf(f, 0.f);
        O[(size_t)(rbase + j) * N + c] = f2bf(f);
      }
    }
  }
}

// ---------------- K9: combine ----------------
__global__ __launch_bounds__(128) void k_combine(
    const u16* __restrict__ eo, const u16* __restrict__ dense_o,
    const float4* __restrict__ tok_wf, const int2* __restrict__ tok_slot,
    float* __restrict__ out)
{
  int t = blockIdx.x;
  int c8 = threadIdx.x;
  float4 wf = tok_wf[t];
  int2 sl = tok_slot[t];
  u16x8 a  = *((const u16x8*)(eo + (size_t)sl.x * D_DIM) + c8);
  u16x8 b  = *((const u16x8*)(eo + (size_t)sl.y * D_DIM) + c8);
  u16x8 dn = *((const u16x8*)(dense_o + (size_t)t * D_DIM) + c8);
  float* op = out + (size_t)t * D_DIM + c8 * 8;
  #pragma unroll
  for (int j = 0; j < 8; ++j) {
    float mo = wf.x * bf2f(a[j]) + wf.y * bf2f(b[j]);
    op[j] = wf.z * mo + wf.w * bf2f(dn[j]);
  }
}

// ---------------- launch ----------------
extern "C" void kernel_launch(void* const* d_in, const int* in_sizes, int n_in,
                              void* d_out, int out_size, void* d_ws, size_t ws_size,
                              hipStream_t stream)
{
  const float* x   = (const float*)d_in[0];
  const float* Wr  = (const float*)d_in[1];
  const float* br  = (const float*)d_in[2];
  const float* Wg  = (const float*)d_in[3];
  const float* bg  = (const float*)d_in[4];
  const float* W1  = (const float*)d_in[5];
  const float* b1  = (const float*)d_in[6];
  const float* W2  = (const float*)d_in[7];
  const float* b2  = (const float*)d_in[8];
  const float* D1  = (const float*)d_in[9];
  const float* d1b = (const float*)d_in[10];
  const float* D2  = (const float*)d_in[11];
  const float* d2b = (const float*)d_in[12];
  float* out = (float*)d_out;

  char* base = (char*)d_ws;
  size_t cur = 0;
  auto alloc = [&](size_t b) -> void* {
    void* p = base + cur; cur = (cur + b + 255) & ~(size_t)255; return p;
  };
  int*    hdr      = (int*)   alloc(256 * sizeof(int));
  int4*   tilemap  = (int4*)  alloc((size_t)RT_MAX * sizeof(int4));
  int4*   tok_sel  = (int4*)  alloc((size_t)T_TOK * sizeof(int4));
  float4* tok_wf   = (float4*)alloc((size_t)T_TOK * sizeof(float4));
  int2*   tok_slot = (int2*)  alloc((size_t)T_TOK * sizeof(int2));
  int*    perm     = (int*)   alloc((size_t)SLOT_MAX * sizeof(int));
  u16*    xb       = (u16*)   alloc((size_t)T_TOK * D_DIM * 2);
  u16*    xg       = (u16*)   alloc((size_t)SLOT_MAX * D_DIM * 2);
  u16*    W1bt     = (u16*)   alloc((size_t)E_NUM * D_DIM * FF_DIM * 2);
  u16*    W2bt     = (u16*)   alloc((size_t)E_NUM * D_DIM * FF_DIM * 2);
  u16*    D1bt     = (u16*)   alloc((size_t)D_DIM * FF_DIM * 2);
  u16*    D2bt     = (u16*)   alloc((size_t)D_DIM * FF_DIM * 2);
  u16*    h_moe    = (u16*)   alloc((size_t)SLOT_MAX * FF_DIM * 2);
  u16*    h_dense  = (u16*)   alloc((size_t)T_TOK * FF_DIM * 2);
  u16*    eo       = (u16*)   alloc((size_t)SLOT_MAX * D_DIM * 2);
  u16*    dense_o  = (u16*)   alloc((size_t)T_TOK * D_DIM * 2);
  (void)in_sizes; (void)n_in; (void)out_size; (void)ws_size; // needs ~467 MB of ws

  k_init   <<<1, 64, 0, stream>>>(hdr);
  k_route  <<<T_TOK / 4, 256, 0, stream>>>(x, Wr, br, Wg, bg, hdr, tok_sel, tok_wf);
  k_offsets<<<1, 256, 0, stream>>>(hdr, tilemap, perm);
  k_scatter<<<T_TOK / 256, 256, 0, stream>>>(tok_sel, hdr, perm, tok_slot);
  k_cast   <<<(T_TOK * D_DIM / 8) / 256, 256, 0, stream>>>(x, xb, T_TOK * D_DIM / 8);
  k_gather <<<SLOT_MAX / 2, 256, 0, stream>>>(xb, perm, hdr, xg);
  k_tcast  <<<dim3(FF_DIM / 64, D_DIM / 64, E_NUM), 256, 0, stream>>>(W1, W1bt, D_DIM, FF_DIM);
  k_tcast  <<<dim3(D_DIM / 64, FF_DIM / 64, E_NUM), 256, 0, stream>>>(W2, W2bt, FF_DIM, D_DIM);
  k_tcast  <<<dim3(FF_DIM / 64, D_DIM / 64, 1), 256, 0, stream>>>(D1, D1bt, D_DIM, FF_DIM);
  k_tcast  <<<dim3(D_DIM / 64, FF_DIM / 64, 1), 256, 0, stream>>>(D2, D2bt, FF_DIM, D_DIM);

  k_gemm<1><<<dim3(FF_DIM / 128, RT_MAX), 256, 0, stream>>>(
      xg, xb, W1bt, D1bt, b1, d1b, h_moe, h_dense, hdr, tilemap,
      D_DIM, FF_DIM, (long)D_DIM * FF_DIM, FF_DIM);
  k_gemm<0><<<dim3(D_DIM / 128, RT_MAX), 256, 0, stream>>>(
      h_moe, h_dense, W2bt, D2bt, b2, d2b, eo, dense_o, hdr, tilemap,
      FF_DIM, D_DIM, (long)D_DIM * FF_DIM, D_DIM);

  k_combine<<<T_TOK, 128, 0, stream>>>(eo, dense_o, tok_wf, tok_slot, out);
}